// Round 3
// baseline (99.769 us; speedup 1.0000x reference)
//
#include <hip/hip_runtime.h>
#include <hip/hip_bf16.h>

// GAT layer, B=4, N=4096, F_in=128, F_out=64.
// out_i = sum_j adj_ij * exp(leaky(s2_i+s1_j)) * Wh_j
//         / ( sum_j adj_ij*exp(..) + 1e-9 * sum_j exp(..) )
// softmax max-subtraction cancels exactly; scores are O(6) so bare exp2 is safe.
// s1/s2 stored pre-scaled by log2(e).

typedef __attribute__((ext_vector_type(8))) short bf16x8;
typedef __attribute__((ext_vector_type(4))) float f32x4;
typedef __attribute__((ext_vector_type(4))) unsigned int u32x4;

#define LOG2E 1.4426950408889634f

__device__ __forceinline__ unsigned short f2bf(float x) {
  union { float f; unsigned int u; } c; c.f = x;
  unsigned int r = c.u + 0x7fffu + ((c.u >> 16) & 1u);  // RNE
  return (unsigned short)(r >> 16);
}
__device__ __forceinline__ float bf2f(unsigned short s) {
  union { unsigned int u; float f; } c; c.u = ((unsigned int)s) << 16; return c.f;
}
__device__ __forceinline__ bf16x8 u2b(u32x4 v) {
  union { u32x4 u; bf16x8 b; } c; c.u = v; return c.b;
}

// ---------------- K1: Wh = h @ W (f32); WhT as bf16 hi/lo [b][64][4096];
//                  s1 = Wh a1 * log2e, s2 = Wh a2 * log2e
__global__ __launch_bounds__(256) void k_wh(
    const float* __restrict__ h, const float* __restrict__ W, const float* __restrict__ a,
    unsigned short* __restrict__ wtHi, unsigned short* __restrict__ wtLo,
    float* __restrict__ s1, float* __restrict__ s2) {
  __shared__ float hs[32][130];
  const int t = threadIdx.x;
  const int b = blockIdx.x >> 7;
  const int row0 = (blockIdx.x & 127) << 5;

  #pragma unroll
  for (int it = 0; it < 4; ++it) {
    int flat = it * 256 + t;
    int r = flat >> 5, q = flat & 31;
    const float4 v = *(const float4*)(h + ((size_t)(b * 4096 + row0 + r)) * 128 + 4 * q);
    hs[r][4*q+0] = v.x; hs[r][4*q+1] = v.y; hs[r][4*q+2] = v.z; hs[r][4*q+3] = v.w;
  }
  __syncthreads();

  const int rg = t >> 4, cg = t & 15;
  float acc[2][4] = {};
  for (int k = 0; k < 128; ++k) {
    float4 wv = *(const float4*)(W + k * 64 + 4 * cg);
    #pragma unroll
    for (int i = 0; i < 2; ++i) {
      float hv = hs[2*rg + i][k];
      acc[i][0] = fmaf(hv, wv.x, acc[i][0]);
      acc[i][1] = fmaf(hv, wv.y, acc[i][1]);
      acc[i][2] = fmaf(hv, wv.z, acc[i][2]);
      acc[i][3] = fmaf(hv, wv.w, acc[i][3]);
    }
  }
  __syncthreads();

  float (*WhF)[68] = (float(*)[68])hs;
  #pragma unroll
  for (int i = 0; i < 2; ++i)
    #pragma unroll
    for (int j = 0; j < 4; ++j)
      WhF[2*rg + i][4*cg + j] = acc[i][j];
  __syncthreads();

  if (t < 32) {
    float x1 = 0.f, x2 = 0.f;
    #pragma unroll 8
    for (int c = 0; c < 64; ++c) {
      float v = WhF[t][c];
      x1 = fmaf(v, a[c], x1);
      x2 = fmaf(v, a[64 + c], x2);
    }
    s1[b * 4096 + row0 + t] = x1 * LOG2E;
    s2[b * 4096 + row0 + t] = x2 * LOG2E;
  }

  const int col = t >> 2, sub = t & 3;
  unsigned short hi[8], lo[8];
  #pragma unroll
  for (int r = 0; r < 8; ++r) {
    float v = WhF[8*sub + r][col];
    unsigned short hb = f2bf(v);
    hi[r] = hb;
    lo[r] = f2bf(v - bf2f(hb));
  }
  unsigned int uh[4], ul[4];
  #pragma unroll
  for (int r = 0; r < 4; ++r) {
    uh[r] = (unsigned)hi[2*r] | ((unsigned)hi[2*r+1] << 16);
    ul[r] = (unsigned)lo[2*r] | ((unsigned)lo[2*r+1] << 16);
  }
  size_t base = ((size_t)(b * 64 + col)) * 4096 + row0 + 8 * sub;
  *(uint4*)(wtHi + base) = make_uint4(uh[0], uh[1], uh[2], uh[3]);
  *(uint4*)(wtLo + base) = make_uint4(ul[0], ul[1], ul[2], ul[3]);
}

// ---------------- K3: out = P @ (WhHi + WhLo), P built on the fly.
// 32 rows x 64 cols per block; 4 waves each own a 16-col block (no B dup).
// B-frags direct global->VGPR (L2-resident); Pw double-buffered; ONE raw
// s_barrier + lgkmcnt(0) per K-step; manual 2x-unrolled pipeline (no shift
// copies -> prefetches stay in flight across steps). adj loads nontemporal.
__global__ __launch_bounds__(256) void k_main(
    const float* __restrict__ adj,
    const unsigned short* __restrict__ wtHi, const unsigned short* __restrict__ wtLo,
    const float* __restrict__ s1, const float* __restrict__ s2,
    float* __restrict__ out) {
  __shared__ unsigned short Pw[2][32 * 72];
  __shared__ float Zs[32], Ss[32];

  const int t = threadIdx.x;
  const int blk = blockIdx.x;
  // XCD swizzle: blocks on one XCD (blk&7) share the same b -> WhT set 1MB/XCD
  const int b = (blk & 7) >> 1;
  const int row0 = (((blk >> 3) + ((blk & 1) << 6))) << 5;   // bijective
  const int lane = t & 63, w = t >> 6;        // wave w owns cols 16w..16w+15
  const int jj = t & 15, prow = t >> 4;       // P-build role
  const int g = lane >> 4, lr = lane & 15;    // mfma fragment role

  const float* adjR0 = adj + ((size_t)(b * 4096 + row0) + prow) * 4096 + 4 * jj;
  const float* adjR1 = adjR0 + (size_t)16 * 4096;
  const float* s1b = s1 + b * 4096 + 4 * jj;
  const float s2v0 = s2[b * 4096 + row0 + prow];
  const float s2v1 = s2[b * 4096 + row0 + 16 + prow];
  const unsigned short* gh = wtHi + ((size_t)(b * 64 + 16 * w + lr)) * 4096 + 8 * g;
  const unsigned short* gl = wtLo + ((size_t)(b * 64 + 16 * w + lr)) * 4096 + 8 * g;

  float z0 = 0.f, z1 = 0.f, sa0 = 0.f, sa1 = 0.f;
  f32x4 acc0 = {0.f, 0.f, 0.f, 0.f}, acc1 = {0.f, 0.f, 0.f, 0.f};

#define LD4(p)  __builtin_nontemporal_load((const f32x4*)(p))
#define LDS1(p) (*(const f32x4*)(p))
#define LDU4(p) (*(const u32x4*)(p))

#define PBUILD(buf, a0, a1, sv) do {                                          \
    {                                                                         \
      float e0 = s2v0 + (sv)[0], e1 = s2v0 + (sv)[1];                         \
      float e2 = s2v0 + (sv)[2], e3 = s2v0 + (sv)[3];                         \
      e0 = fmaxf(e0, 0.2f*e0); e1 = fmaxf(e1, 0.2f*e1);                       \
      e2 = fmaxf(e2, 0.2f*e2); e3 = fmaxf(e3, 0.2f*e3);                       \
      float p0 = exp2f(e0), p1 = exp2f(e1), p2 = exp2f(e2), p3 = exp2f(e3);   \
      float w0 = (a0)[0]*p0, w1 = (a0)[1]*p1, w2 = (a0)[2]*p2, w3 = (a0)[3]*p3;\
      z0 += (p0+p1)+(p2+p3); sa0 += (w0+w1)+(w2+w3);                          \
      ushort4 pk; pk.x=f2bf(w0); pk.y=f2bf(w1); pk.z=f2bf(w2); pk.w=f2bf(w3); \
      *(ushort4*)&Pw[buf][prow*72 + 4*jj] = pk;                               \
    }                                                                         \
    {                                                                         \
      float e0 = s2v1 + (sv)[0], e1 = s2v1 + (sv)[1];                         \
      float e2 = s2v1 + (sv)[2], e3 = s2v1 + (sv)[3];                         \
      e0 = fmaxf(e0, 0.2f*e0); e1 = fmaxf(e1, 0.2f*e1);                       \
      e2 = fmaxf(e2, 0.2f*e2); e3 = fmaxf(e3, 0.2f*e3);                       \
      float p0 = exp2f(e0), p1 = exp2f(e1), p2 = exp2f(e2), p3 = exp2f(e3);   \
      float w0 = (a1)[0]*p0, w1 = (a1)[1]*p1, w2 = (a1)[2]*p2, w3 = (a1)[3]*p3;\
      z1 += (p0+p1)+(p2+p3); sa1 += (w0+w1)+(w2+w3);                          \
      ushort4 pk; pk.x=f2bf(w0); pk.y=f2bf(w1); pk.z=f2bf(w2); pk.w=f2bf(w3); \
      *(ushort4*)&Pw[buf][(16+prow)*72 + 4*jj] = pk;                          \
    }                                                                         \
  } while (0)

#define SYNC() do {                                                           \
    asm volatile("s_waitcnt lgkmcnt(0)" ::: "memory");                        \
    __builtin_amdgcn_sched_barrier(0);                                        \
    __builtin_amdgcn_s_barrier();                                             \
    __builtin_amdgcn_sched_barrier(0);                                        \
  } while (0)

#define MFMA_HALF(buf, BH0, BL0, BH1, BL1) do {                               \
    const bf16x8 afL0 = *(const bf16x8*)&Pw[buf][lr*72 + 8*g];                \
    const bf16x8 afL1 = *(const bf16x8*)&Pw[buf][lr*72 + 32 + 8*g];           \
    const bf16x8 afH0 = *(const bf16x8*)&Pw[buf][(16+lr)*72 + 8*g];           \
    const bf16x8 afH1 = *(const bf16x8*)&Pw[buf][(16+lr)*72 + 32 + 8*g];      \
    acc0 = __builtin_amdgcn_mfma_f32_16x16x32_bf16(afL0, u2b(BH0), acc0, 0,0,0); \
    acc1 = __builtin_amdgcn_mfma_f32_16x16x32_bf16(afH0, u2b(BH0), acc1, 0,0,0); \
    acc0 = __builtin_amdgcn_mfma_f32_16x16x32_bf16(afL0, u2b(BL0), acc0, 0,0,0); \
    acc1 = __builtin_amdgcn_mfma_f32_16x16x32_bf16(afH0, u2b(BL0), acc1, 0,0,0); \
    acc0 = __builtin_amdgcn_mfma_f32_16x16x32_bf16(afL1, u2b(BH1), acc0, 0,0,0); \
    acc1 = __builtin_amdgcn_mfma_f32_16x16x32_bf16(afH1, u2b(BH1), acc1, 0,0,0); \
    acc0 = __builtin_amdgcn_mfma_f32_16x16x32_bf16(afL1, u2b(BL1), acc0, 0,0,0); \
    acc1 = __builtin_amdgcn_mfma_f32_16x16x32_bf16(afH1, u2b(BL1), acc1, 0,0,0); \
  } while (0)

  // prologue: adj for steps 0 (A-set) and 1 (B-set); B-frags for step 0 (A-set)
  f32x4 aA0 = LD4(adjR0), aA1 = LD4(adjR1), sA = LDS1(s1b);
  f32x4 aB0 = LD4(adjR0 + 64), aB1 = LD4(adjR1 + 64), sB = LDS1(s1b + 64);
  u32x4 bh0A = LDU4(gh),      bl0A = LDU4(gl);
  u32x4 bh1A = LDU4(gh + 32), bl1A = LDU4(gl + 32);
  u32x4 bh0B, bl0B, bh1B, bl1B;

  for (int j = 0; j < 32; ++j) {
    const int s0 = 2 * j;
    { // ---- step s0 (buf 0) ----
      const int kB = ((s0 + 1) & 63) << 6;           // B-frags for step s0+1
      bh0B = LDU4(gh + kB);      bl0B = LDU4(gl + kB);
      bh1B = LDU4(gh + kB + 32); bl1B = LDU4(gl + kB + 32);
      PBUILD(0, aA0, aA1, sA);                       // last use of A-set adj
      const int kA = ((s0 + 2) & 63) << 6;           // adj for step s0+2
      aA0 = LD4(adjR0 + kA); aA1 = LD4(adjR1 + kA); sA = LDS1(s1b + kA);
      SYNC();
      MFMA_HALF(0, bh0A, bl0A, bh1A, bl1A);          // last use of A-set B
    }
    { // ---- step s0+1 (buf 1) ----
      const int kB = ((s0 + 2) & 63) << 6;           // B-frags for step s0+2
      bh0A = LDU4(gh + kB);      bl0A = LDU4(gl + kB);
      bh1A = LDU4(gh + kB + 32); bl1A = LDU4(gl + kB + 32);
      PBUILD(1, aB0, aB1, sB);
      const int kA = ((s0 + 3) & 63) << 6;           // adj for step s0+3
      aB0 = LD4(adjR0 + kA); aB1 = LD4(adjR1 + kA); sB = LDS1(s1b + kA);
      SYNC();
      MFMA_HALF(1, bh0B, bl0B, bh1B, bl1B);
    }
  }

  // reduce Z/S across the 16 lanes sharing a row
  #pragma unroll
  for (int m = 1; m < 16; m <<= 1) {
    z0 += __shfl_xor(z0, m);  z1 += __shfl_xor(z1, m);
    sa0 += __shfl_xor(sa0, m); sa1 += __shfl_xor(sa1, m);
  }
  if (jj == 0) {
    Zs[prow] = z0;      Ss[prow] = sa0;
    Zs[16 + prow] = z1; Ss[16 + prow] = sa1;
  }
  __syncthreads();

  // epilogue: scale by 1/(S + eps*Z); wave w owns cols 16w..16w+15
  #pragma unroll
  for (int reg = 0; reg < 4; ++reg) {
    const int r0 = 4 * g + reg;
    const int r1 = 16 + 4 * g + reg;
    const float inv0 = 1.0f / (Ss[r0] + 1e-9f * Zs[r0]);
    const float inv1 = 1.0f / (Ss[r1] + 1e-9f * Zs[r1]);
    const size_t ob = ((size_t)(b * 4096 + row0 + r0)) * 64 + 16 * w + lr;
    out[ob] = acc0[reg] * inv0;
    out[ob + (size_t)16 * 64] = acc1[reg] * inv1;
  }
}

extern "C" void kernel_launch(void* const* d_in, const int* in_sizes, int n_in,
                              void* d_out, int out_size, void* d_ws, size_t ws_size,
                              hipStream_t stream) {
  const float* h   = (const float*)d_in[0];
  const float* adj = (const float*)d_in[1];
  const float* W   = (const float*)d_in[2];
  const float* a   = (const float*)d_in[3];
  float* out = (float*)d_out;

  unsigned short* wtHi = (unsigned short*)d_ws;
  unsigned short* wtLo = wtHi + (size_t)4 * 64 * 4096;
  float* s1 = (float*)(wtLo + (size_t)4 * 64 * 4096);
  float* s2 = s1 + 16384;

  k_wh  <<<512, 256, 0, stream>>>(h, W, a, wtHi, wtLo, s1, s2);
  k_main<<<512, 256, 0, stream>>>(adj, wtHi, wtLo, s1, s2, out);
}

// Round 4
// 95.417 us; speedup vs baseline: 1.0456x; 1.0456x over previous
//
#include <hip/hip_runtime.h>
#include <hip/hip_bf16.h>

// GAT layer, B=4, N=4096, F_in=128, F_out=64.
// out_i = sum_j adj_ij * exp(leaky(s2_i+s1_j)) * Wh_j
//         / ( sum_j adj_ij*exp(..) + 1e-9 * sum_j exp(..) )
// softmax max-subtraction cancels exactly; scores are O(6) so bare exp2 is safe.
// s1/s2 stored pre-scaled by log2(e).

typedef __attribute__((ext_vector_type(8))) short bf16x8;
typedef __attribute__((ext_vector_type(4))) float f32x4;

#define LOG2E 1.4426950408889634f

__device__ __forceinline__ unsigned short f2bf(float x) {
  union { float f; unsigned int u; } c; c.f = x;
  unsigned int r = c.u + 0x7fffu + ((c.u >> 16) & 1u);  // RNE
  return (unsigned short)(r >> 16);
}
__device__ __forceinline__ float bf2f(unsigned short s) {
  union { unsigned int u; float f; } c; c.u = ((unsigned int)s) << 16; return c.f;
}
__device__ __forceinline__ void gload16(const void* g, void* l) {
  __builtin_amdgcn_global_load_lds(
      (const __attribute__((address_space(1))) void*)g,
      (__attribute__((address_space(3))) void*)l, 16, 0, 0);
}

// ---------------- K1: Wh = h @ W (f32); WhT as bf16 hi/lo [b][64][4096] (plain
// [col][k] layout); s1 = Wh a1 * log2e, s2 = Wh a2 * log2e
__global__ __launch_bounds__(256) void k_wh(
    const float* __restrict__ h, const float* __restrict__ W, const float* __restrict__ a,
    unsigned short* __restrict__ wtHi, unsigned short* __restrict__ wtLo,
    float* __restrict__ s1, float* __restrict__ s2) {
  __shared__ float hs[32][130];
  const int t = threadIdx.x;
  const int b = blockIdx.x >> 7;
  const int row0 = (blockIdx.x & 127) << 5;

  #pragma unroll
  for (int it = 0; it < 4; ++it) {
    int flat = it * 256 + t;
    int r = flat >> 5, q = flat & 31;
    const float4 v = *(const float4*)(h + ((size_t)(b * 4096 + row0 + r)) * 128 + 4 * q);
    hs[r][4*q+0] = v.x; hs[r][4*q+1] = v.y; hs[r][4*q+2] = v.z; hs[r][4*q+3] = v.w;
  }
  __syncthreads();

  const int rg = t >> 4, cg = t & 15;
  float acc[2][4] = {};
  for (int k = 0; k < 128; ++k) {
    float4 wv = *(const float4*)(W + k * 64 + 4 * cg);
    #pragma unroll
    for (int i = 0; i < 2; ++i) {
      float hv = hs[2*rg + i][k];
      acc[i][0] = fmaf(hv, wv.x, acc[i][0]);
      acc[i][1] = fmaf(hv, wv.y, acc[i][1]);
      acc[i][2] = fmaf(hv, wv.z, acc[i][2]);
      acc[i][3] = fmaf(hv, wv.w, acc[i][3]);
    }
  }
  __syncthreads();

  float (*WhF)[68] = (float(*)[68])hs;
  #pragma unroll
  for (int i = 0; i < 2; ++i)
    #pragma unroll
    for (int j = 0; j < 4; ++j)
      WhF[2*rg + i][4*cg + j] = acc[i][j];
  __syncthreads();

  if (t < 32) {
    float x1 = 0.f, x2 = 0.f;
    #pragma unroll 8
    for (int c = 0; c < 64; ++c) {
      float v = WhF[t][c];
      x1 = fmaf(v, a[c], x1);
      x2 = fmaf(v, a[64 + c], x2);
    }
    s1[b * 4096 + row0 + t] = x1 * LOG2E;
    s2[b * 4096 + row0 + t] = x2 * LOG2E;
  }

  const int col = t >> 2, sub = t & 3;
  unsigned short hi[8], lo[8];
  #pragma unroll
  for (int r = 0; r < 8; ++r) {
    float v = WhF[8*sub + r][col];
    unsigned short hb = f2bf(v);
    hi[r] = hb;
    lo[r] = f2bf(v - bf2f(hb));
  }
  unsigned int uh[4], ul[4];
  #pragma unroll
  for (int r = 0; r < 4; ++r) {
    uh[r] = (unsigned)hi[2*r] | ((unsigned)hi[2*r+1] << 16);
    ul[r] = (unsigned)lo[2*r] | ((unsigned)lo[2*r+1] << 16);
  }
  size_t base = ((size_t)(b * 64 + col)) * 4096 + row0 + 8 * sub;
  *(uint4*)(wtHi + base) = make_uint4(uh[0], uh[1], uh[2], uh[3]);
  *(uint4*)(wtLo + base) = make_uint4(ul[0], ul[1], ul[2], ul[3]);
}

// ---------------- K3: out = P @ (WhHi + WhLo), P built on the fly.
// 32 rows x 64 cols per block; wave w owns cols [16w,16w+16).
// B via global_load_lds (pre-swizzled source, XOR bank-swizzle on read),
// triple-buffered; P double-buffered; ONE raw barrier + counted vmcnt(10)
// per K-step (adj HBM prefetch never force-drained).
__global__ __launch_bounds__(256) void k_main(
    const float* __restrict__ adj,
    const unsigned short* __restrict__ wtHi, const unsigned short* __restrict__ wtLo,
    const float* __restrict__ s1, const float* __restrict__ s2,
    float* __restrict__ out) {
  __shared__ unsigned short Blds[3][2][4096];  // [buf][hi/lo][col*64 + k'] 48KB
  __shared__ unsigned short Pws[2][2304];      // [buf][row*72 + k] 9KB
  __shared__ float Zs[32], Ss[32];

  const int t = threadIdx.x;
  const int blk = blockIdx.x;
  // XCD swizzle: one b per XCD-pair -> WhT working set 2MB/XCD (fits L2)
  const int b = (blk & 7) >> 1;
  const int row0 = (((blk >> 3) + ((blk & 1) << 6))) << 5;   // bijective
  const int l = t & 63, w = t >> 6;
  const int jj = t & 15, prow = t >> 4;       // P-build role
  const int g = l >> 4, lr = l & 15;          // mfma fragment role

  const float* adjR0 = adj + ((size_t)(b * 4096 + row0) + prow) * 4096 + 4 * jj;
  const float* adjR1 = adjR0 + (size_t)16 * 4096;
  const float* s1b = s1 + b * 4096 + 4 * jj;
  const float s2v0 = s2[b * 4096 + row0 + prow];
  const float s2v1 = s2[b * 4096 + row0 + 16 + prow];

  // gload_lds source (pre-swizzled): col = c'*32 + w*8 + (l>>3),
  // k-offset = 8*((l&7)^(l>>3)); LDS dest is linear lane*16B.
  const int colw = w * 8 + (l >> 3);
  const int kx = 8 * ((l & 7) ^ (l >> 3));
  const unsigned short* srcH0 = wtHi + ((size_t)(b * 64 + colw)) * 4096 + kx;
  const unsigned short* srcH1 = srcH0 + (size_t)32 * 4096;
  const unsigned short* srcL0 = wtLo + ((size_t)(b * 64 + colw)) * 4096 + kx;
  const unsigned short* srcL1 = srcL0 + (size_t)32 * 4096;

  // swizzled read offsets (shorts): ((kk*32+8g) ^ ((lr&7)<<3)) within row
  const int colr = 16 * w + lr;
  const int bo_k0 = colr * 64 + ((8 * g) ^ ((lr & 7) << 3));
  const int bo_k1 = colr * 64 + (((32 + 8 * g)) ^ ((lr & 7) << 3));
  const int ao_l0 = lr * 72 + 8 * g;
  const int ao_l1 = lr * 72 + 32 + 8 * g;
  const int ao_h0 = (16 + lr) * 72 + 8 * g;
  const int ao_h1 = (16 + lr) * 72 + 32 + 8 * g;

  unsigned short* BldsBase = &Blds[0][0][0];
  unsigned short* PwsBase = &Pws[0][0];

  float z0 = 0.f, z1 = 0.f, sa0 = 0.f, sa1 = 0.f;
  f32x4 acc0 = {0.f, 0.f, 0.f, 0.f}, acc1 = {0.f, 0.f, 0.f, 0.f};

#define NT4(p) __builtin_nontemporal_load((const f32x4*)(p))

#define PB(pbv, A0, A1, SV) do {                                              \
    unsigned short* Pd = PwsBase + (pbv) * 2304;                              \
    {                                                                         \
      float e0 = s2v0 + (SV)[0], e1 = s2v0 + (SV)[1];                         \
      float e2 = s2v0 + (SV)[2], e3 = s2v0 + (SV)[3];                         \
      e0 = fmaxf(e0, 0.2f*e0); e1 = fmaxf(e1, 0.2f*e1);                       \
      e2 = fmaxf(e2, 0.2f*e2); e3 = fmaxf(e3, 0.2f*e3);                       \
      float p0 = exp2f(e0), p1 = exp2f(e1), p2 = exp2f(e2), p3 = exp2f(e3);   \
      float w0 = (A0)[0]*p0, w1 = (A0)[1]*p1, w2 = (A0)[2]*p2, w3 = (A0)[3]*p3;\
      z0 += (p0+p1)+(p2+p3); sa0 += (w0+w1)+(w2+w3);                          \
      ushort4 pk; pk.x=f2bf(w0); pk.y=f2bf(w1); pk.z=f2bf(w2); pk.w=f2bf(w3); \
      *(ushort4*)(Pd + prow*72 + 4*jj) = pk;                                  \
    }                                                                         \
    {                                                                         \
      float e0 = s2v1 + (SV)[0], e1 = s2v1 + (SV)[1];                         \
      float e2 = s2v1 + (SV)[2], e3 = s2v1 + (SV)[3];                         \
      e0 = fmaxf(e0, 0.2f*e0); e1 = fmaxf(e1, 0.2f*e1);                       \
      e2 = fmaxf(e2, 0.2f*e2); e3 = fmaxf(e3, 0.2f*e3);                       \
      float p0 = exp2f(e0), p1 = exp2f(e1), p2 = exp2f(e2), p3 = exp2f(e3);   \
      float w0 = (A1)[0]*p0, w1 = (A1)[1]*p1, w2 = (A1)[2]*p2, w3 = (A1)[3]*p3;\
      z1 += (p0+p1)+(p2+p3); sa1 += (w0+w1)+(w2+w3);                          \
      ushort4 pk; pk.x=f2bf(w0); pk.y=f2bf(w1); pk.z=f2bf(w2); pk.w=f2bf(w3); \
      *(ushort4*)(Pd + (16+prow)*72 + 4*jj) = pk;                             \
    }                                                                         \
  } while (0)

#define BODY(A0, A1, SV) {                                                    \
    const int kB = ((s + 1) & 63) << 6;                                       \
    unsigned short* dB = BldsBase + nbW * 8192 + w * 512;                     \
    gload16(srcH0 + kB, dB);                                                  \
    gload16(srcH1 + kB, dB + 2048);                                           \
    gload16(srcL0 + kB, dB + 4096);                                           \
    gload16(srcL1 + kB, dB + 6144);                                           \
    __builtin_amdgcn_sched_barrier(0);  /* pin: B issued before adj below */  \
    PB(pb, A0, A1, SV);                                                       \
    const int kA = ((s + 2) & 63) << 6;                                       \
    A0 = NT4(adjR0 + kA); A1 = NT4(adjR1 + kA);                               \
    SV = *(const f32x4*)(s1b + kA);                                           \
    asm volatile("s_waitcnt vmcnt(10) lgkmcnt(0)" ::: "memory");              \
    __builtin_amdgcn_sched_barrier(0);                                        \
    __builtin_amdgcn_s_barrier();                                             \
    __builtin_amdgcn_sched_barrier(0);                                        \
    const unsigned short* Br = BldsBase + nbR * 8192;                         \
    const unsigned short* Pr = PwsBase + pb * 2304;                           \
    bf16x8 afL0 = *(const bf16x8*)(Pr + ao_l0);                               \
    bf16x8 afL1 = *(const bf16x8*)(Pr + ao_l1);                               \
    bf16x8 afH0 = *(const bf16x8*)(Pr + ao_h0);                               \
    bf16x8 afH1 = *(const bf16x8*)(Pr + ao_h1);                               \
    bf16x8 bh0 = *(const bf16x8*)(Br + bo_k0);                                \
    bf16x8 bh1 = *(const bf16x8*)(Br + bo_k1);                                \
    bf16x8 bl0 = *(const bf16x8*)(Br + 4096 + bo_k0);                         \
    bf16x8 bl1 = *(const bf16x8*)(Br + 4096 + bo_k1);                         \
    acc0 = __builtin_amdgcn_mfma_f32_16x16x32_bf16(afL0, bh0, acc0, 0,0,0);   \
    acc1 = __builtin_amdgcn_mfma_f32_16x16x32_bf16(afH0, bh0, acc1, 0,0,0);   \
    acc0 = __builtin_amdgcn_mfma_f32_16x16x32_bf16(afL0, bl0, acc0, 0,0,0);   \
    acc1 = __builtin_amdgcn_mfma_f32_16x16x32_bf16(afH0, bl0, acc1, 0,0,0);   \
    acc0 = __builtin_amdgcn_mfma_f32_16x16x32_bf16(afL1, bh1, acc0, 0,0,0);   \
    acc1 = __builtin_amdgcn_mfma_f32_16x16x32_bf16(afH1, bh1, acc1, 0,0,0);   \
    acc0 = __builtin_amdgcn_mfma_f32_16x16x32_bf16(afL1, bl1, acc0, 0,0,0);   \
    acc1 = __builtin_amdgcn_mfma_f32_16x16x32_bf16(afH1, bl1, acc1, 0,0,0);   \
    nbR = nbW; nbW = (nbW == 2) ? 0 : nbW + 1;                                \
    pb ^= 1;                                                                  \
    ++s;                                                                      \
  }

  int nbR = 0, nbW = 1, pb = 0, s = 0;
  // prologue: B(0) first (so vmcnt counting holds at SYNC(0)), then adj(0,1)
  {
    unsigned short* d0 = BldsBase + w * 512;
    gload16(srcH0, d0);
    gload16(srcH1, d0 + 2048);
    gload16(srcL0, d0 + 4096);
    gload16(srcL1, d0 + 6144);
  }
  __builtin_amdgcn_sched_barrier(0);
  f32x4 aA0 = NT4(adjR0), aA1 = NT4(adjR1), sA = *(const f32x4*)s1b;
  f32x4 aB0 = NT4(adjR0 + 64), aB1 = NT4(adjR1 + 64), sB = *(const f32x4*)(s1b + 64);

  for (int jit = 0; jit < 32; ++jit) {
    BODY(aA0, aA1, sA)
    BODY(aB0, aB1, sB)
  }

  // reduce Z/S across the 16 lanes sharing a row
  #pragma unroll
  for (int m = 1; m < 16; m <<= 1) {
    z0 += __shfl_xor(z0, m);  z1 += __shfl_xor(z1, m);
    sa0 += __shfl_xor(sa0, m); sa1 += __shfl_xor(sa1, m);
  }
  if (jj == 0) {
    Zs[prow] = z0;      Ss[prow] = sa0;
    Zs[16 + prow] = z1; Ss[16 + prow] = sa1;
  }
  __syncthreads();

  // epilogue: scale by 1/(S + eps*Z); wave w owns cols 16w..16w+15
  #pragma unroll
  for (int reg = 0; reg < 4; ++reg) {
    const int r0 = 4 * g + reg;
    const int r1 = 16 + 4 * g + reg;
    const float inv0 = 1.0f / (Ss[r0] + 1e-9f * Zs[r0]);
    const float inv1 = 1.0f / (Ss[r1] + 1e-9f * Zs[r1]);
    const size_t ob = ((size_t)(b * 4096 + row0 + r0)) * 64 + 16 * w + lr;
    out[ob] = acc0[reg] * inv0;
    out[ob + (size_t)16 * 64] = acc1[reg] * inv1;
  }
}

extern "C" void kernel_launch(void* const* d_in, const int* in_sizes, int n_in,
                              void* d_out, int out_size, void* d_ws, size_t ws_size,
                              hipStream_t stream) {
  const float* h   = (const float*)d_in[0];
  const float* adj = (const float*)d_in[1];
  const float* W   = (const float*)d_in[2];
  const float* a   = (const float*)d_in[3];
  float* out = (float*)d_out;

  unsigned short* wtHi = (unsigned short*)d_ws;
  unsigned short* wtLo = wtHi + (size_t)4 * 64 * 4096;
  float* s1 = (float*)(wtLo + (size_t)4 * 64 * 4096);
  float* s2 = s1 + 16384;

  k_wh  <<<512, 256, 0, stream>>>(h, W, a, wtHi, wtLo, s1, s2);
  k_main<<<512, 256, 0, stream>>>(adj, wtHi, wtLo, s1, s2, out);
}